// Round 6
// baseline (433.856 us; speedup 1.0000x reference)
//
#include <hip/hip_runtime.h>
#include <math.h>

typedef unsigned short u16;
typedef unsigned int u32;
typedef __attribute__((ext_vector_type(4))) float f32x4;
typedef __attribute__((ext_vector_type(8))) unsigned short u16x8;
typedef __attribute__((ext_vector_type(4))) unsigned short u16x4;
typedef __attribute__((ext_vector_type(8))) __bf16 bf16x8;

#define DEV __device__ __forceinline__

constexpr int S = 2048;
constexpr int HIDDEN = 5120;
constexpr int H = 16;
constexpr int NOPE = 128, ROPE_D = 64, VD = 128;
constexpr int QKD = NOPE + ROPE_D;  // 192
constexpr int QLORA = 1536, KVLORA = 512;
constexpr int KVA_N = KVLORA + ROPE_D;  // 576
constexpr float SCALING = 0.11472134f;

DEV u16 f2b(float f) {
  u32 u = __builtin_bit_cast(u32, f);
  u32 r = u + 0x7FFFu + ((u >> 16) & 1u);
  return (u16)(r >> 16);
}
DEV float b2f(u16 h) { return __builtin_bit_cast(float, (u32)h << 16); }

DEV void store_out(float* p, float v) { *p = v; }
DEV void store_out(u16* p, float v) { *p = f2b(v); }

DEV void gload_lds16(const u16* g, u16* l) {
  auto* gp = (const __attribute__((address_space(1))) u16*)g;
  auto* lp = (__attribute__((address_space(3))) u16*)l;
  __builtin_amdgcn_global_load_lds(gp, lp, 16, 0, 0);
}

#define SWZ(row, col) ((col) ^ (((row) & 7) << 3))

// ---------------- elementwise f32 -> bf16 ----------------
__global__ __launch_bounds__(256) void k_convert(const float* __restrict__ in,
                                                 u16* __restrict__ out, int n) {
  int i = (blockIdx.x * 256 + threadIdx.x) * 4;
  if (i >= n) return;
  f32x4 v = *reinterpret_cast<const f32x4*>(in + i);
  u16x4 o;
  o[0] = f2b(v[0]); o[1] = f2b(v[1]); o[2] = f2b(v[2]); o[3] = f2b(v[3]);
  *reinterpret_cast<u16x4*>(out + i) = o;
}

// ---------------- transpose f32[R][C] -> bf16[C][R] ----------------
__global__ __launch_bounds__(256) void k_transpose(const float* __restrict__ in,
                                                   u16* __restrict__ out, int R, int C) {
  __shared__ float t[32][33];
  int c0 = blockIdx.x * 32, r0 = blockIdx.y * 32;
  int tx = threadIdx.x, ty = threadIdx.y;
  for (int r = ty; r < 32; r += 8)
    t[r][tx] = in[(size_t)(r0 + r) * C + c0 + tx];
  __syncthreads();
  for (int r = ty; r < 32; r += 8)
    out[(size_t)(c0 + r) * R + r0 + tx] = f2b(t[tx][r]);
}

// ---------------- YaRN rope tables ----------------
__global__ __launch_bounds__(256) void k_rope_tables(float* __restrict__ cs,
                                                     float* __restrict__ sn) {
  int idx = blockIdx.x * 256 + threadIdx.x;
  if (idx >= S * 32) return;
  int s = idx >> 5, j = idx & 31;
  double pf = pow(10000.0, (double)j / 32.0);
  double inv_extra = 1.0 / pf;
  double inv_interp = 1.0 / (40.0 * pf);
  double twopi = 6.283185307179586476925286766559;
  double lnb2 = 2.0 * log(10000.0);
  double lowd = floor(64.0 * log(4096.0 / (32.0 * twopi)) / lnb2);
  if (lowd < 0.0) lowd = 0.0;
  double highd = ceil(64.0 * log(4096.0 / twopi) / lnb2);
  if (highd > 63.0) highd = 63.0;
  double denom = highd - lowd;
  if (denom < 0.001) denom = 0.001;
  double ramp = ((double)j - lowd) / denom;
  ramp = ramp < 0.0 ? 0.0 : (ramp > 1.0 ? 1.0 : ramp);
  float invf = (float)(inv_interp * ramp + inv_extra * (1.0 - ramp));
  float fr = (float)s * invf;
  cs[idx] = cosf(fr);
  sn[idx] = sinf(fr);
}

// ---------------- bf16 GEMM body: BMx256 tile, 8 waves, 4-deep pipeline ----
// C[*,N] = A[*,K] * BT[N,K]^T.  8 waves (512 thr), wave grid 2(M) x 4(N).
// Per-wave out: (BM/2) x 64.  LDS linear, source-granule swizzle (G21).
template <int BM, typename OutT>
DEV void gemm_body(u16* Al, u16* Bl, const u16* __restrict__ A,
                   const u16* __restrict__ BT, OutT* __restrict__ C,
                   int N, int K, int mbase, int nbase) {
  constexpr int MF = BM / 32;        // M-frags per wave
  constexpr int ABUF = BM * 32;      // elems per A buffer
  constexpr int BBUF = 256 * 32;
  constexpr int L = (BM == 256) ? 4 : 3;  // gloads per thread per K-step
  const int tid = threadIdx.x;
  const int lane = tid & 63, wave = tid >> 6;
  const int wm = wave >> 2, wn = wave & 3;
  const int lr = lane & 15, lk = lane >> 4;
  const int srowB = wave * 32 + (lane >> 2);
  const int srowA = (BM == 256) ? srowB : (wave * 16 + (lane >> 2));
  const int skoff = ((lane & 3) ^ ((lane >> 3) & 3)) * 8;  // source swizzle
  const int swlk8 = (lk ^ ((lr >> 1) & 3)) * 8;            // read swizzle
  const u16* aptr = A + (size_t)(mbase + srowA) * K + skoff;
  const u16* bptr = BT + (size_t)(nbase + srowB) * K + skoff;
  u16* alw = Al + wave * ((BM == 256) ? 1024 : 512);
  u16* blw = Bl + wave * 1024;

  auto STAGE = [&](int b, int kk) {
    gload_lds16(aptr + kk, alw + b * ABUF);
    if constexpr (BM == 256) gload_lds16(aptr + (size_t)16 * K + kk, alw + b * ABUF + 512);
    gload_lds16(bptr + kk, blw + b * BBUF);
    gload_lds16(bptr + (size_t)16 * K + kk, blw + b * BBUF + 512);
  };

  f32x4 acc[MF][4];
#pragma unroll
  for (int mf = 0; mf < MF; ++mf)
#pragma unroll
    for (int nf = 0; nf < 4; ++nf) acc[mf][nf] = {0.f, 0.f, 0.f, 0.f};

  const int nt = K >> 5;  // >= 4 for all our shapes (min 16)
  STAGE(0, 0);
  STAGE(1, 32);
  STAGE(2, 64);
  STAGE(3, 96);
  for (int t = 0; t < nt; ++t) {
    const int cur = t & 3;
    const int rem = nt - 1 - t;
    if constexpr (L == 4) {
      if (rem >= 3)      asm volatile("s_waitcnt vmcnt(12)" ::: "memory");
      else if (rem == 2) asm volatile("s_waitcnt vmcnt(8)" ::: "memory");
      else if (rem == 1) asm volatile("s_waitcnt vmcnt(4)" ::: "memory");
      else               asm volatile("s_waitcnt vmcnt(0)" ::: "memory");
    } else {
      if (rem >= 3)      asm volatile("s_waitcnt vmcnt(9)" ::: "memory");
      else if (rem == 2) asm volatile("s_waitcnt vmcnt(6)" ::: "memory");
      else if (rem == 1) asm volatile("s_waitcnt vmcnt(3)" ::: "memory");
      else               asm volatile("s_waitcnt vmcnt(0)" ::: "memory");
    }
    __builtin_amdgcn_s_barrier();
    const u16* Ac = Al + cur * ABUF + (wm * (BM / 2)) * 32;
    const u16* Bc = Bl + cur * BBUF + (wn * 64) * 32;
    bf16x8 af[MF];
#pragma unroll
    for (int mf = 0; mf < MF; ++mf)
      af[mf] = *reinterpret_cast<const bf16x8*>(Ac + (mf * 16 + lr) * 32 + swlk8);
    __builtin_amdgcn_s_setprio(1);
#pragma unroll
    for (int nf = 0; nf < 4; ++nf) {
      bf16x8 bfr = *reinterpret_cast<const bf16x8*>(Bc + (nf * 16 + lr) * 32 + swlk8);
#pragma unroll
      for (int mf = 0; mf < MF; ++mf)
        acc[mf][nf] = __builtin_amdgcn_mfma_f32_16x16x32_bf16(af[mf], bfr, acc[mf][nf], 0, 0, 0);
    }
    __builtin_amdgcn_s_setprio(0);
    __builtin_amdgcn_s_barrier();
    if (t + 4 < nt) STAGE(cur, (t + 4) * 32);
  }

#pragma unroll
  for (int mf = 0; mf < MF; ++mf)
#pragma unroll
    for (int nf = 0; nf < 4; ++nf) {
      int col = nbase + wn * 64 + nf * 16 + lr;
      if (col < N) {
#pragma unroll
        for (int r = 0; r < 4; ++r) {
          int row = mbase + wm * (BM / 2) + mf * 16 + lk * 4 + r;
          store_out(&C[(size_t)row * N + col], acc[mf][nf][r]);
        }
      }
    }
}

// down-proj fused: grid 144 = 16 rows(BM=128) x 9 cols (6 q + 3 kv).
// row = bid & 15 -> XCD (bid&7) keeps its A row-panels L2-resident.
__global__ __launch_bounds__(512) void k_gemm_dp(const u16* __restrict__ A,
                                                 const u16* __restrict__ Bq,
                                                 const u16* __restrict__ Bkv,
                                                 float* __restrict__ q_lat,
                                                 float* __restrict__ latent) {
  __shared__ u16 Al[4 * 128 * 32];
  __shared__ u16 Bl[4 * 256 * 32];
  int bid = blockIdx.x;
  int row = bid & 15, ct = bid >> 4;
  if (ct < 6)
    gemm_body<128>(Al, Bl, A, Bq, q_lat, QLORA, HIDDEN, row * 128, ct * 256);
  else
    gemm_body<128>(Al, Bl, A, Bkv, latent, KVA_N, HIDDEN, row * 128, (ct - 6) * 256);
}

// up-proj grouped: grid 224 = 96 (q: 8x12) + 128 (kv: 8x16), BM=256.
__global__ __launch_bounds__(512) void k_gemm_up(const u16* __restrict__ Aq,
                                                 const u16* __restrict__ Bq,
                                                 u16* __restrict__ Cq,
                                                 const u16* __restrict__ Akv,
                                                 const u16* __restrict__ Bkv,
                                                 u16* __restrict__ Ckv) {
  __shared__ u16 Al[4 * 256 * 32];
  __shared__ u16 Bl[4 * 256 * 32];
  int bx = blockIdx.x;
  if (bx < 96)
    gemm_body<256>(Al, Bl, Aq, Bq, Cq, H * QKD, QLORA, (bx & 7) * 256, (bx >> 3) * 256);
  else {
    int l = bx - 96;
    gemm_body<256>(Al, Bl, Akv, Bkv, Ckv, H * 256, KVLORA, (l & 7) * 256, (l >> 3) * 256);
  }
}

// out-proj: grid 160 = 8 rows x 20 cols, BM=256.
__global__ __launch_bounds__(512) void k_gemm_out(const u16* __restrict__ A,
                                                  const u16* __restrict__ BT,
                                                  float* __restrict__ C) {
  __shared__ u16 Al[4 * 256 * 32];
  __shared__ u16 Bl[4 * 256 * 32];
  int bid = blockIdx.x;
  gemm_body<256>(Al, Bl, A, BT, C, HIDDEN, H * VD, (bid & 7) * 256, (bid >> 3) * 256);
}

// ---------------- RMSNorm fp32 -> bf16 ----------------
__global__ __launch_bounds__(256) void k_rmsnorm(const float* __restrict__ x,
                                                 const float* __restrict__ w,
                                                 u16* __restrict__ y, int ncols, int instride) {
  int row = blockIdx.x, tid = threadIdx.x;
  const float* xr = x + (size_t)row * instride;
  float ss = 0.f;
  for (int i = tid * 4; i < ncols; i += 1024) {
    f32x4 v = *reinterpret_cast<const f32x4*>(xr + i);
    ss += v[0] * v[0] + v[1] * v[1] + v[2] * v[2] + v[3] * v[3];
  }
  for (int off = 32; off > 0; off >>= 1) ss += __shfl_down(ss, off);
  __shared__ float red[4];
  if ((tid & 63) == 0) red[tid >> 6] = ss;
  __syncthreads();
  ss = red[0] + red[1] + red[2] + red[3];
  float sc = rsqrtf(ss / (float)ncols + 1e-6f);
  u16* yr = y + (size_t)row * ncols;
  for (int i = tid * 4; i < ncols; i += 1024) {
    f32x4 v = *reinterpret_cast<const f32x4*>(xr + i);
    u16x4 o;
    o[0] = f2b(v[0] * sc * w[i]);
    o[1] = f2b(v[1] * sc * w[i + 1]);
    o[2] = f2b(v[2] * sc * w[i + 2]);
    o[3] = f2b(v[3] * sc * w[i + 3]);
    *reinterpret_cast<u16x4*>(yr + i) = o;
  }
}

// ---------------- build qf [H][S][192], kf [H][S][192] with RoPE ----------------
__global__ __launch_bounds__(256) void k_build_qkf(const u16* __restrict__ qn,
                                                   const u16* __restrict__ kv,
                                                   const float* __restrict__ latent,
                                                   const float* __restrict__ cs,
                                                   const float* __restrict__ sn,
                                                   u16* __restrict__ qf, u16* __restrict__ kf) {
  int s = blockIdx.x, tid = threadIdx.x;
  for (int idx = tid; idx < H * NOPE; idx += 256) {
    int h = idx >> 7, dd = idx & 127;
    qf[((size_t)h * S + s) * QKD + dd] = qn[(size_t)s * (H * QKD) + h * QKD + dd];
    kf[((size_t)h * S + s) * QKD + dd] = kv[(size_t)s * (H * 256) + h * 256 + dd];
  }
  for (int idx = tid; idx < H * 32; idx += 256) {
    int h = idx >> 5, j = idx & 31;
    float c = cs[s * 32 + j], si = sn[s * 32 + j];
    float x1 = b2f(qn[(size_t)s * (H * QKD) + h * QKD + NOPE + 2 * j]);
    float x2 = b2f(qn[(size_t)s * (H * QKD) + h * QKD + NOPE + 2 * j + 1]);
    qf[((size_t)h * S + s) * QKD + NOPE + 2 * j] = f2b(x1 * c - x2 * si);
    qf[((size_t)h * S + s) * QKD + NOPE + 2 * j + 1] = f2b(x2 * c + x1 * si);
    float k1 = latent[(size_t)s * KVA_N + KVLORA + 2 * j];
    float k2 = latent[(size_t)s * KVA_N + KVLORA + 2 * j + 1];
    kf[((size_t)h * S + s) * QKD + NOPE + 2 * j] = f2b(k1 * c - k2 * si);
    kf[((size_t)h * S + s) * QKD + NOPE + 2 * j + 1] = f2b(k2 * c + k1 * si);
  }
}

// ---------------- build vt [H][128][S] (transposed V) ----------------
__global__ void k_build_vt(const u16* __restrict__ kv, u16* __restrict__ vt) {
  __shared__ u16 t[32][33];
  int s0 = blockIdx.x * 32, d0 = blockIdx.y * 32, h = blockIdx.z;
  int tx = threadIdx.x, ty = threadIdx.y;
  for (int r = ty; r < 32; r += 8)
    t[r][tx] = kv[(size_t)(s0 + r) * (H * 256) + h * 256 + NOPE + d0 + tx];
  __syncthreads();
  for (int r = ty; r < 32; r += 8)
    vt[((size_t)h * VD + d0 + r) * S + s0 + tx] = t[tx][r];
}

// ---------------- flash attention (causal), per head ----------------
__global__ __launch_bounds__(256) void k_attn(const u16* __restrict__ qf,
                                              const u16* __restrict__ kf,
                                              const u16* __restrict__ vt,
                                              u16* __restrict__ attn) {
  const int bidx = blockIdx.x;
  const int j = bidx & 31;
  const int h = bidx >> 5;
  const int qt = (h < 8) ? j : 31 - j;
  const int qbase = qt * 64;
  const int tid = threadIdx.x, wave = tid >> 6, lane = tid & 63;
  const int lr = lane & 15, lk = lane >> 4;
  __shared__ u16 Kl[64][192];
  __shared__ u16 Vl[128][64];
  __shared__ u16 Pl[4][16][64];

  int krow_[6], kofs_[6], vrow_[4], vofs_[4];
#pragma unroll
  for (int i = 0; i < 6; ++i) { int c = tid + i * 256; krow_[i] = c / 24; kofs_[i] = (c % 24) * 8; }
#pragma unroll
  for (int i = 0; i < 4; ++i) { int c = tid + i * 256; vrow_[i] = c >> 3; vofs_[i] = (c & 7) * 8; }
  const u16* kfh = kf + (size_t)h * S * QKD;
  const u16* vth = vt + (size_t)h * VD * S;

  bf16x8 qfrag[6];
  const u16* qrow = qf + ((size_t)h * S + qbase + wave * 16 + lr) * QKD;
#pragma unroll
  for (int d = 0; d < 6; ++d)
    qfrag[d] = *reinterpret_cast<const bf16x8*>(qrow + d * 32 + lk * 8);

  u16x8 kreg[6], vreg[4];
#pragma unroll
  for (int i = 0; i < 6; ++i)
    kreg[i] = *reinterpret_cast<const u16x8*>(kfh + (size_t)krow_[i] * QKD + kofs_[i]);
#pragma unroll
  for (int i = 0; i < 4; ++i)
    vreg[i] = *reinterpret_cast<const u16x8*>(vth + (size_t)vrow_[i] * S + vofs_[i]);

  f32x4 o[8];
#pragma unroll
  for (int f = 0; f < 8; ++f) o[f] = {0.f, 0.f, 0.f, 0.f};
  float m_[4] = {-__builtin_inff(), -__builtin_inff(), -__builtin_inff(), -__builtin_inff()};
  float l_[4] = {0.f, 0.f, 0.f, 0.f};

  const int ktiles = qt + 1;
  for (int kt = 0; kt < ktiles; ++kt) {
    const int kbase = kt * 64;
    __builtin_amdgcn_s_barrier();
#pragma unroll
    for (int i = 0; i < 6; ++i)
      *reinterpret_cast<u16x8*>(&Kl[krow_[i]][SWZ(krow_[i], kofs_[i])]) = kreg[i];
#pragma unroll
    for (int i = 0; i < 4; ++i)
      *reinterpret_cast<u16x8*>(&Vl[vrow_[i]][SWZ(vrow_[i], vofs_[i])]) = vreg[i];
    if (kt + 1 < ktiles) {
      const int nb = kbase + 64;
#pragma unroll
      for (int i = 0; i < 6; ++i)
        kreg[i] = *reinterpret_cast<const u16x8*>(kfh + (size_t)(nb + krow_[i]) * QKD + kofs_[i]);
#pragma unroll
      for (int i = 0; i < 4; ++i)
        vreg[i] = *reinterpret_cast<const u16x8*>(vth + (size_t)vrow_[i] * S + nb + vofs_[i]);
    }
    asm volatile("s_waitcnt lgkmcnt(0)" ::: "memory");
    __builtin_amdgcn_s_barrier();

    f32x4 sacc[4];
#pragma unroll
    for (int nf = 0; nf < 4; ++nf) sacc[nf] = {0.f, 0.f, 0.f, 0.f};
    __builtin_amdgcn_s_setprio(1);
#pragma unroll
    for (int nf = 0; nf < 4; ++nf)
#pragma unroll
      for (int dk = 0; dk < 6; ++dk) {
        int krow = nf * 16 + lr;
        bf16x8 b = *reinterpret_cast<const bf16x8*>(&Kl[krow][SWZ(krow, dk * 32 + lk * 8)]);
        sacc[nf] = __builtin_amdgcn_mfma_f32_16x16x32_bf16(qfrag[dk], b, sacc[nf], 0, 0, 0);
      }
    __builtin_amdgcn_s_setprio(0);

    float sv[4][4];
    float rowmax[4] = {-__builtin_inff(), -__builtin_inff(), -__builtin_inff(), -__builtin_inff()};
#pragma unroll
    for (int nf = 0; nf < 4; ++nf) {
      int kcol = kbase + nf * 16 + lr;
#pragma unroll
      for (int r = 0; r < 4; ++r) {
        float v = sacc[nf][r] * SCALING;
        int qrow_g = qbase + wave * 16 + lk * 4 + r;
        if (kcol > qrow_g) v = -__builtin_inff();
        sv[nf][r] = v;
        rowmax[r] = fmaxf(rowmax[r], v);
      }
    }
#pragma unroll
    for (int r = 0; r < 4; ++r) {
#pragma unroll
      for (int off = 1; off < 16; off <<= 1)
        rowmax[r] = fmaxf(rowmax[r], __shfl_xor(rowmax[r], off));
    }
    float alpha[4], rowsum[4] = {0.f, 0.f, 0.f, 0.f};
#pragma unroll
    for (int r = 0; r < 4; ++r) {
      float mn = fmaxf(m_[r], rowmax[r]);
      alpha[r] = __expf(m_[r] - mn);
      m_[r] = mn;
    }
#pragma unroll
    for (int nf = 0; nf < 4; ++nf)
#pragma unroll
      for (int r = 0; r < 4; ++r) {
        float p = __expf(sv[nf][r] - m_[r]);
        sv[nf][r] = p;
        rowsum[r] += p;
      }
#pragma unroll
    for (int r = 0; r < 4; ++r) {
#pragma unroll
      for (int off = 1; off < 16; off <<= 1) rowsum[r] += __shfl_xor(rowsum[r], off);
      l_[r] = l_[r] * alpha[r] + rowsum[r];
    }
#pragma unroll
    for (int nf = 0; nf < 4; ++nf)
#pragma unroll
      for (int r = 0; r < 4; ++r) {
        int prow = lk * 4 + r;
        Pl[wave][prow][SWZ(prow, nf * 16 + lr)] = f2b(sv[nf][r]);
      }
#pragma unroll
    for (int f = 0; f < 8; ++f)
#pragma unroll
      for (int r = 0; r < 4; ++r) o[f][r] *= alpha[r];

    __builtin_amdgcn_s_setprio(1);
#pragma unroll
    for (int kk = 0; kk < 2; ++kk) {
      bf16x8 pa = *reinterpret_cast<const bf16x8*>(&Pl[wave][lr][SWZ(lr, kk * 32 + lk * 8)]);
#pragma unroll
      for (int f = 0; f < 8; ++f) {
        int vrow = f * 16 + lr;
        bf16x8 b = *reinterpret_cast<const bf16x8*>(&Vl[vrow][SWZ(vrow, kk * 32 + lk * 8)]);
        o[f] = __builtin_amdgcn_mfma_f32_16x16x32_bf16(pa, b, o[f], 0, 0, 0);
      }
    }
    __builtin_amdgcn_s_setprio(0);
  }

#pragma unroll
  for (int f = 0; f < 8; ++f)
#pragma unroll
    for (int r = 0; r < 4; ++r) {
      int row = qbase + wave * 16 + lk * 4 + r;
      float val = o[f][r] / l_[r];
      attn[(size_t)row * (H * VD) + h * VD + f * 16 + lr] = f2b(val);
    }
}

// ---------------- host launch ----------------
extern "C" void kernel_launch(void* const* d_in, const int* in_sizes, int n_in,
                              void* d_out, int out_size, void* d_ws, size_t ws_size,
                              hipStream_t stream) {
  (void)in_sizes; (void)n_in; (void)out_size; (void)ws_size;
  const float* hidden    = (const float*)d_in[1];
  const float* w_q_a     = (const float*)d_in[2];
  const float* q_a_ln_w  = (const float*)d_in[3];
  const float* w_q_b     = (const float*)d_in[4];
  const float* w_kv_a    = (const float*)d_in[5];
  const float* kv_a_ln_w = (const float*)d_in[6];
  const float* w_kv_b    = (const float*)d_in[7];
  const float* w_o       = (const float*)d_in[8];
  float* out = (float*)d_out;

  char* ws = (char*)d_ws;
  size_t off = 0;
  auto alloc = [&](size_t bytes) {
    size_t o = off;
    off += (bytes + 255) & ~(size_t)255;
    return o;
  };
  constexpr int KVA_PAD = 768;  // 576 padded to 3x256 (unguarded DMA reads)
  size_t o_hs    = alloc((size_t)S * HIDDEN * 2);        // hs bf16; later reused as qf
  size_t o_btqa  = alloc((size_t)QLORA * HIDDEN * 2);    // later (with o_btkva) bt_o
  size_t o_btkva = alloc((size_t)KVA_PAD * HIDDEN * 2);
  size_t o_btqb  = alloc((size_t)(H * QKD) * QLORA * 2);
  size_t o_btkvb = alloc((size_t)(H * 256) * KVLORA * 2);
  size_t o_qlat  = alloc((size_t)S * QLORA * 4);         // later reused as attn
  size_t o_lat   = alloc((size_t)S * KVA_N * 4);
  size_t o_qln   = alloc((size_t)S * QLORA * 2);
  size_t o_kvln  = alloc((size_t)S * KVLORA * 2);
  size_t o_qn    = alloc((size_t)S * (H * QKD) * 2);
  size_t o_kv    = alloc((size_t)S * (H * 256) * 2);
  size_t o_kf    = alloc((size_t)H * S * QKD * 2);
  size_t o_vt    = alloc((size_t)H * VD * S * 2);
  size_t o_cs    = alloc((size_t)S * 32 * 4);
  size_t o_sn    = alloc((size_t)S * 32 * 4);

  u16* hs_bf  = (u16*)(ws + o_hs);
  u16* bt_qa  = (u16*)(ws + o_btqa);
  u16* bt_kva = (u16*)(ws + o_btkva);
  u16* bt_qb  = (u16*)(ws + o_btqb);
  u16* bt_kvb = (u16*)(ws + o_btkvb);
  float* q_lat  = (float*)(ws + o_qlat);
  float* latent = (float*)(ws + o_lat);
  u16* q_ln  = (u16*)(ws + o_qln);
  u16* kv_ln = (u16*)(ws + o_kvln);
  u16* qn    = (u16*)(ws + o_qn);
  u16* kvb   = (u16*)(ws + o_kv);
  u16* kf    = (u16*)(ws + o_kf);
  u16* vt    = (u16*)(ws + o_vt);
  float* cs = (float*)(ws + o_cs);
  float* sn = (float*)(ws + o_sn);
  // aliases (lifetimes verified: source buffers dead before alias written)
  u16* qf   = (u16*)(ws + o_hs);
  u16* bt_o = (u16*)(ws + o_btqa);  // spans btqa+btkva (21 MB needed, 23.6 avail)
  u16* attn = (u16*)(ws + o_qlat);

  dim3 t256(256), t32x8(32, 8);

  // prep
  k_convert<<<(S * HIDDEN / 4 + 255) / 256, t256, 0, stream>>>(hidden, hs_bf, S * HIDDEN);
  k_transpose<<<dim3(QLORA / 32, HIDDEN / 32), t32x8, 0, stream>>>(w_q_a, bt_qa, HIDDEN, QLORA);
  k_transpose<<<dim3(KVA_N / 32, HIDDEN / 32), t32x8, 0, stream>>>(w_kv_a, bt_kva, HIDDEN, KVA_N);
  k_transpose<<<dim3(H * QKD / 32, QLORA / 32), t32x8, 0, stream>>>(w_q_b, bt_qb, QLORA, H * QKD);
  k_transpose<<<dim3(H * 256 / 32, KVLORA / 32), t32x8, 0, stream>>>(w_kv_b, bt_kvb, KVLORA, H * 256);
  k_rope_tables<<<(S * 32 + 255) / 256, t256, 0, stream>>>(cs, sn);

  // down-projections: fused, 144 blocks (16 rows x [6 q + 3 kv] cols)
  k_gemm_dp<<<dim3(144), dim3(512), 0, stream>>>(hs_bf, bt_qa, bt_kva, q_lat, latent);

  // norms
  k_rmsnorm<<<S, t256, 0, stream>>>(q_lat, q_a_ln_w, q_ln, QLORA, QLORA);
  k_rmsnorm<<<S, t256, 0, stream>>>(latent, kv_a_ln_w, kv_ln, KVLORA, KVA_N);

  // up-projections: 224 blocks (96 q + 128 kv), 256^2 tiles
  k_gemm_up<<<dim3(224), dim3(512), 0, stream>>>(q_ln, bt_qb, qn, kv_ln, bt_kvb, kvb);

  // rearrange + RoPE
  k_build_qkf<<<S, t256, 0, stream>>>(qn, kvb, latent, cs, sn, qf, kf);
  k_build_vt<<<dim3(S / 32, VD / 32, H), t32x8, 0, stream>>>(kvb, vt);

  // transpose w_o (into region freed after down-projections)
  k_transpose<<<dim3(HIDDEN / 32, (H * VD) / 32), t32x8, 0, stream>>>(w_o, bt_o, H * VD, HIDDEN);

  // attention (flat 512-block grid, work-balanced qt mapping)
  k_attn<<<dim3(512), t256, 0, stream>>>(qf, kf, vt, attn);

  // output projection: 160 blocks (8 rows x 20 cols), 256^2 tiles
  k_gemm_out<<<dim3(160), dim3(512), 0, stream>>>(attn, bt_o, out);
}

// Round 7
// 358.596 us; speedup vs baseline: 1.2099x; 1.2099x over previous
//
#include <hip/hip_runtime.h>
#include <math.h>

typedef unsigned short u16;
typedef unsigned int u32;
typedef __attribute__((ext_vector_type(4))) float f32x4;
typedef __attribute__((ext_vector_type(8))) unsigned short u16x8;
typedef __attribute__((ext_vector_type(4))) unsigned short u16x4;
typedef __attribute__((ext_vector_type(8))) __bf16 bf16x8;

#define DEV __device__ __forceinline__

constexpr int S = 2048;
constexpr int HIDDEN = 5120;
constexpr int H = 16;
constexpr int NOPE = 128, ROPE_D = 64, VD = 128;
constexpr int QKD = NOPE + ROPE_D;  // 192
constexpr int QLORA = 1536, KVLORA = 512;
constexpr int KVA_N = KVLORA + ROPE_D;  // 576
constexpr float SCALING = 0.11472134f;

DEV u16 f2b(float f) {
  u32 u = __builtin_bit_cast(u32, f);
  u32 r = u + 0x7FFFu + ((u >> 16) & 1u);
  return (u16)(r >> 16);
}
DEV float b2f(u16 h) { return __builtin_bit_cast(float, (u32)h << 16); }

DEV void store_out(float* p, float v) { *p = v; }
DEV void store_out(u16* p, float v) { *p = f2b(v); }

DEV void gload_lds16(const u16* g, u16* l) {
  auto* gp = (const __attribute__((address_space(1))) u16*)g;
  auto* lp = (__attribute__((address_space(3))) u16*)l;
  __builtin_amdgcn_global_load_lds(gp, lp, 16, 0, 0);
}

#define SWZ(row, col) ((col) ^ (((row) & 7) << 3))

// ================= fused prep: convert + 4 transposes + rope tables ========
// roles (flat blocks): [0,10240) convert hs; then transposes
// wqa 7680 (48x160), wkva 2880 (18x160), wqb 4608 (96x48), wkvb 2048 (128x16),
// rope 256.  total 27712.
DEV void transpose_tile(const float* __restrict__ in, u16* __restrict__ out,
                        int R, int C, int c0, int r0, int tid, float (*tl)[33]) {
  int tx = tid & 31, ty = tid >> 5;
  for (int r = ty; r < 32; r += 8)
    tl[r][tx] = in[(size_t)(r0 + r) * C + c0 + tx];
  __syncthreads();
  for (int r = ty; r < 32; r += 8)
    out[(size_t)(c0 + r) * R + r0 + tx] = f2b(tl[tx][r]);
}

__global__ __launch_bounds__(256) void k_prep(const float* __restrict__ hidden, u16* __restrict__ hs_bf,
                                              const float* __restrict__ w_q_a, u16* __restrict__ bt_qa,
                                              const float* __restrict__ w_kv_a, u16* __restrict__ bt_kva,
                                              const float* __restrict__ w_q_b, u16* __restrict__ bt_qb,
                                              const float* __restrict__ w_kv_b, u16* __restrict__ bt_kvb,
                                              float* __restrict__ cs, float* __restrict__ sn) {
  __shared__ float tl[32][33];
  int b = blockIdx.x, tid = threadIdx.x;
  if (b < 10240) {  // convert
    int i = (b * 256 + tid) * 4;
    f32x4 v = *reinterpret_cast<const f32x4*>(hidden + i);
    u16x4 o;
    o[0] = f2b(v[0]); o[1] = f2b(v[1]); o[2] = f2b(v[2]); o[3] = f2b(v[3]);
    *reinterpret_cast<u16x4*>(hs_bf + i) = o;
    return;
  }
  b -= 10240;
  if (b < 7680) {
    transpose_tile(w_q_a, bt_qa, HIDDEN, QLORA, (b % 48) * 32, (b / 48) * 32, tid, tl);
    return;
  }
  b -= 7680;
  if (b < 2880) {
    transpose_tile(w_kv_a, bt_kva, HIDDEN, KVA_N, (b % 18) * 32, (b / 18) * 32, tid, tl);
    return;
  }
  b -= 2880;
  if (b < 4608) {
    transpose_tile(w_q_b, bt_qb, QLORA, H * QKD, (b % 96) * 32, (b / 96) * 32, tid, tl);
    return;
  }
  b -= 4608;
  if (b < 2048) {
    transpose_tile(w_kv_b, bt_kvb, KVLORA, H * 256, (b % 128) * 32, (b / 128) * 32, tid, tl);
    return;
  }
  b -= 2048;  // rope tables, b < 256
  int idx = b * 256 + tid;
  int s = idx >> 5, j = idx & 31;
  double pf = pow(10000.0, (double)j / 32.0);
  double inv_extra = 1.0 / pf;
  double inv_interp = 1.0 / (40.0 * pf);
  double twopi = 6.283185307179586476925286766559;
  double lnb2 = 2.0 * log(10000.0);
  double lowd = floor(64.0 * log(4096.0 / (32.0 * twopi)) / lnb2);
  if (lowd < 0.0) lowd = 0.0;
  double highd = ceil(64.0 * log(4096.0 / twopi) / lnb2);
  if (highd > 63.0) highd = 63.0;
  double denom = highd - lowd;
  if (denom < 0.001) denom = 0.001;
  double ramp = ((double)j - lowd) / denom;
  ramp = ramp < 0.0 ? 0.0 : (ramp > 1.0 ? 1.0 : ramp);
  float invf = (float)(inv_interp * ramp + inv_extra * (1.0 - ramp));
  float fr = (float)s * invf;
  cs[idx] = cosf(fr);
  sn[idx] = sinf(fr);
}

// ================= bf16 GEMM body (R4-proven): 2-deep dbuf + counted vmcnt ==
template <typename OutT>
DEV void gemm_body(u16* Al, u16* Bl, const u16* __restrict__ A,
                   const u16* __restrict__ BT, OutT* __restrict__ C,
                   int N, int Kstride, int Klen, int mbase, int nbase) {
  const int tid = threadIdx.x;
  const int lane = tid & 63, wave = tid >> 6;
  const int wr = wave >> 1, wc = wave & 1;
  const int lr = lane & 15, lk = lane >> 4;
  const int srow = wave * 32 + (lane >> 2);
  const int skoff = (((lane & 3) ^ ((lane >> 3) & 3))) * 8;  // source swizzle
  const int swlk8 = (lk ^ ((lr >> 1) & 3)) * 8;              // read swizzle
  const u16* aptr = A + (size_t)(mbase + srow) * Kstride + skoff;
  const u16* bptr = BT + (size_t)(nbase + srow) * Kstride + skoff;
  u16* alw = Al + wave * (32 * 32);
  u16* blw = Bl + wave * (32 * 32);

  auto STAGE = [&](int b, int kk) {
    gload_lds16(aptr + kk, alw + b * 4096);
    gload_lds16(aptr + (size_t)16 * Kstride + kk, alw + b * 4096 + 16 * 32);
    gload_lds16(bptr + kk, blw + b * 4096);
    gload_lds16(bptr + (size_t)16 * Kstride + kk, blw + b * 4096 + 16 * 32);
  };

  f32x4 acc[4][4];
#pragma unroll
  for (int mf = 0; mf < 4; ++mf)
#pragma unroll
    for (int nf = 0; nf < 4; ++nf) acc[mf][nf] = {0.f, 0.f, 0.f, 0.f};

  const int nt = Klen >> 5;
  STAGE(0, 0);
  STAGE(1, 32);
  for (int t = 0; t < nt; ++t) {
    const int cur = t & 1;
    if (t + 1 < nt)
      asm volatile("s_waitcnt vmcnt(4)" ::: "memory");
    else
      asm volatile("s_waitcnt vmcnt(0)" ::: "memory");
    __builtin_amdgcn_s_barrier();
    const u16* Ac = Al + cur * 4096;
    const u16* Bc = Bl + cur * 4096;
    bf16x8 af[4], bfr[4];
#pragma unroll
    for (int mf = 0; mf < 4; ++mf)
      af[mf] = *reinterpret_cast<const bf16x8*>(Ac + (wr * 64 + mf * 16 + lr) * 32 + swlk8);
#pragma unroll
    for (int nf = 0; nf < 4; ++nf)
      bfr[nf] = *reinterpret_cast<const bf16x8*>(Bc + (wc * 64 + nf * 16 + lr) * 32 + swlk8);
#pragma unroll
    for (int mf = 0; mf < 4; ++mf)
#pragma unroll
      for (int nf = 0; nf < 4; ++nf)
        acc[mf][nf] = __builtin_amdgcn_mfma_f32_16x16x32_bf16(af[mf], bfr[nf], acc[mf][nf], 0, 0, 0);
    __builtin_amdgcn_s_barrier();
    if (t + 2 < nt) STAGE(cur, (t + 2) * 32);
  }

#pragma unroll
  for (int mf = 0; mf < 4; ++mf)
#pragma unroll
    for (int nf = 0; nf < 4; ++nf) {
      int col = nbase + wc * 64 + nf * 16 + lr;
      if (col < N) {
#pragma unroll
        for (int r = 0; r < 4; ++r) {
          int row = mbase + wr * 64 + mf * 16 + lk * 4 + r;
          store_out(&C[(size_t)row * N + col], acc[mf][nf][r]);
        }
      }
    }
}

template <typename OutT>
__global__ __launch_bounds__(256) void k_gemm(const u16* __restrict__ A,
                                              const u16* __restrict__ BT,
                                              OutT* __restrict__ C, int N, int K) {
  __shared__ u16 Al[2 * 128 * 32];
  __shared__ u16 Bl[2 * 128 * 32];
  gemm_body(Al, Bl, A, BT, C, N, K, K, blockIdx.y * 128, blockIdx.x * 128);
}

template <typename OutT>
__global__ __launch_bounds__(256) void k_gemm2(const u16* __restrict__ A0, const u16* __restrict__ B0,
                                               OutT* __restrict__ C0, int N0, int K0, int nbx0,
                                               const u16* __restrict__ A1, const u16* __restrict__ B1,
                                               OutT* __restrict__ C1, int N1, int K1) {
  __shared__ u16 Al[2 * 128 * 32];
  __shared__ u16 Bl[2 * 128 * 32];
  int bx = blockIdx.x;
  if (bx < nbx0)
    gemm_body(Al, Bl, A0, B0, C0, N0, K0, K0, blockIdx.y * 128, bx * 128);
  else
    gemm_body(Al, Bl, A1, B1, C1, N1, K1, K1, blockIdx.y * 128, (bx - nbx0) * 128);
}

// down-proj, split-K=2: both GEMMs, both splits, one launch (544 blocks)
__global__ __launch_bounds__(256) void k_gemm_dp(const u16* __restrict__ A,
                                                 const u16* __restrict__ Bq,
                                                 const u16* __restrict__ Bkv,
                                                 float* __restrict__ q0, float* __restrict__ q1,
                                                 float* __restrict__ l0, float* __restrict__ l1) {
  __shared__ u16 Al[2 * 128 * 32];
  __shared__ u16 Bl[2 * 128 * 32];
  constexpr int KH = HIDDEN / 2;  // 2560
  int bx = blockIdx.x;
  int split = bx >= 17;
  int j = bx - split * 17;
  const u16* As = A + split * KH;
  if (j < 12) {
    gemm_body(Al, Bl, As, Bq + split * KH, split ? q1 : q0, QLORA, HIDDEN, KH,
              blockIdx.y * 128, j * 128);
  } else {
    gemm_body(Al, Bl, As, Bkv + split * KH, split ? l1 : l0, KVA_N, HIDDEN, KH,
              blockIdx.y * 128, (j - 12) * 128);
  }
}

// ================= fused mid: 2x rmsnorm(split-K reduce) + w_o transpose ====
DEV void rmsnorm2_row(const float* __restrict__ x0, const float* __restrict__ x1,
                      const float* __restrict__ w, u16* __restrict__ y,
                      int ncols, int instride, int row, int tid, float* red) {
  const float* xr0 = x0 + (size_t)row * instride;
  const float* xr1 = x1 + (size_t)row * instride;
  float ss = 0.f;
  for (int i = tid * 4; i < ncols; i += 1024) {
    f32x4 a = *reinterpret_cast<const f32x4*>(xr0 + i);
    f32x4 b = *reinterpret_cast<const f32x4*>(xr1 + i);
    f32x4 v = a + b;
    ss += v[0] * v[0] + v[1] * v[1] + v[2] * v[2] + v[3] * v[3];
  }
  for (int off = 32; off > 0; off >>= 1) ss += __shfl_down(ss, off);
  if ((tid & 63) == 0) red[tid >> 6] = ss;
  __syncthreads();
  ss = red[0] + red[1] + red[2] + red[3];
  float sc = rsqrtf(ss / (float)ncols + 1e-6f);
  u16* yr = y + (size_t)row * ncols;
  for (int i = tid * 4; i < ncols; i += 1024) {
    f32x4 a = *reinterpret_cast<const f32x4*>(xr0 + i);
    f32x4 b = *reinterpret_cast<const f32x4*>(xr1 + i);
    f32x4 v = a + b;
    u16x4 o;
    o[0] = f2b(v[0] * sc * w[i]);
    o[1] = f2b(v[1] * sc * w[i + 1]);
    o[2] = f2b(v[2] * sc * w[i + 2]);
    o[3] = f2b(v[3] * sc * w[i + 3]);
    *reinterpret_cast<u16x4*>(yr + i) = o;
  }
}

__global__ __launch_bounds__(256) void k_mid(const float* __restrict__ q0, const float* __restrict__ q1,
                                             const float* __restrict__ qw, u16* __restrict__ q_ln,
                                             const float* __restrict__ l0, const float* __restrict__ l1,
                                             const float* __restrict__ kw, u16* __restrict__ kv_ln,
                                             const float* __restrict__ w_o, u16* __restrict__ bt_o) {
  __shared__ float red[4];
  __shared__ float tl[32][33];
  int b = blockIdx.x, tid = threadIdx.x;
  if (b < 2048) {
    rmsnorm2_row(q0, q1, qw, q_ln, QLORA, QLORA, b, tid, red);
    return;
  }
  if (b < 4096) {
    rmsnorm2_row(l0, l1, kw, kv_ln, KVLORA, KVA_N, b - 2048, tid, red);
    return;
  }
  int u = b - 4096;  // w_o transpose: R=H*VD=2048, C=HIDDEN=5120, 160x64 tiles
  transpose_tile(w_o, bt_o, H * VD, HIDDEN, (u % 160) * 32, (u / 160) * 32, tid, tl);
}

// ================= fused build: qf/kf (+RoPE) + vt transpose ================
__global__ __launch_bounds__(256) void k_build(const u16* __restrict__ qn,
                                               const u16* __restrict__ kv,
                                               const float* __restrict__ lat0,
                                               const float* __restrict__ lat1,
                                               const float* __restrict__ cs,
                                               const float* __restrict__ sn,
                                               u16* __restrict__ qf, u16* __restrict__ kf,
                                               u16* __restrict__ vt) {
  __shared__ u16 tv[32][33];
  int b = blockIdx.x, tid = threadIdx.x;
  if (b < 2048) {
    int s = b;
    for (int idx = tid; idx < H * NOPE; idx += 256) {
      int h = idx >> 7, dd = idx & 127;
      qf[((size_t)h * S + s) * QKD + dd] = qn[(size_t)s * (H * QKD) + h * QKD + dd];
      kf[((size_t)h * S + s) * QKD + dd] = kv[(size_t)s * (H * 256) + h * 256 + dd];
    }
    for (int idx = tid; idx < H * 32; idx += 256) {
      int h = idx >> 5, j = idx & 31;
      float c = cs[s * 32 + j], si = sn[s * 32 + j];
      float x1 = b2f(qn[(size_t)s * (H * QKD) + h * QKD + NOPE + 2 * j]);
      float x2 = b2f(qn[(size_t)s * (H * QKD) + h * QKD + NOPE + 2 * j + 1]);
      qf[((size_t)h * S + s) * QKD + NOPE + 2 * j] = f2b(x1 * c - x2 * si);
      qf[((size_t)h * S + s) * QKD + NOPE + 2 * j + 1] = f2b(x2 * c + x1 * si);
      float k1 = lat0[(size_t)s * KVA_N + KVLORA + 2 * j] + lat1[(size_t)s * KVA_N + KVLORA + 2 * j];
      float k2 = lat0[(size_t)s * KVA_N + KVLORA + 2 * j + 1] + lat1[(size_t)s * KVA_N + KVLORA + 2 * j + 1];
      kf[((size_t)h * S + s) * QKD + NOPE + 2 * j] = f2b(k1 * c - k2 * si);
      kf[((size_t)h * S + s) * QKD + NOPE + 2 * j + 1] = f2b(k2 * c + k1 * si);
    }
    return;
  }
  int bb = b - 2048;  // vt: [64 s-tiles][4 d-tiles][16 heads]
  int s0 = (bb & 63) * 32, d0 = ((bb >> 6) & 3) * 32, h = bb >> 8;
  int tx = tid & 31, ty = tid >> 5;
  for (int r = ty; r < 32; r += 8)
    tv[r][tx] = kv[(size_t)(s0 + r) * (H * 256) + h * 256 + NOPE + d0 + tx];
  __syncthreads();
  for (int r = ty; r < 32; r += 8)
    vt[((size_t)h * VD + d0 + r) * S + s0 + tx] = tv[tx][r];
}

// ================= flash attention (causal), per head =======================
__global__ __launch_bounds__(256) void k_attn(const u16* __restrict__ qf,
                                              const u16* __restrict__ kf,
                                              const u16* __restrict__ vt,
                                              u16* __restrict__ attn) {
  const int bidx = blockIdx.x;
  const int j = bidx & 31;
  const int h = bidx >> 5;
  const int qt = (h < 8) ? j : 31 - j;
  const int qbase = qt * 64;
  const int tid = threadIdx.x, wave = tid >> 6, lane = tid & 63;
  const int lr = lane & 15, lk = lane >> 4;
  __shared__ u16 Kl[64][192];
  __shared__ u16 Vl[128][64];
  __shared__ u16 Pl[4][16][64];

  int krow_[6], kofs_[6], vrow_[4], vofs_[4];
#pragma unroll
  for (int i = 0; i < 6; ++i) { int c = tid + i * 256; krow_[i] = c / 24; kofs_[i] = (c % 24) * 8; }
#pragma unroll
  for (int i = 0; i < 4; ++i) { int c = tid + i * 256; vrow_[i] = c >> 3; vofs_[i] = (c & 7) * 8; }
  const u16* kfh = kf + (size_t)h * S * QKD;
  const u16* vth = vt + (size_t)h * VD * S;

  bf16x8 qfrag[6];
  const u16* qrow = qf + ((size_t)h * S + qbase + wave * 16 + lr) * QKD;
#pragma unroll
  for (int d = 0; d < 6; ++d)
    qfrag[d] = *reinterpret_cast<const bf16x8*>(qrow + d * 32 + lk * 8);

  u16x8 kreg[6], vreg[4];
#pragma unroll
  for (int i = 0; i < 6; ++i)
    kreg[i] = *reinterpret_cast<const u16x8*>(kfh + (size_t)krow_[i] * QKD + kofs_[i]);
#pragma unroll
  for (int i = 0; i < 4; ++i)
    vreg[i] = *reinterpret_cast<const u16x8*>(vth + (size_t)vrow_[i] * S + vofs_[i]);

  f32x4 o[8];
#pragma unroll
  for (int f = 0; f < 8; ++f) o[f] = {0.f, 0.f, 0.f, 0.f};
  float m_[4] = {-__builtin_inff(), -__builtin_inff(), -__builtin_inff(), -__builtin_inff()};
  float l_[4] = {0.f, 0.f, 0.f, 0.f};

  const int ktiles = qt + 1;
  for (int kt = 0; kt < ktiles; ++kt) {
    const int kbase = kt * 64;
    __builtin_amdgcn_s_barrier();
#pragma unroll
    for (int i = 0; i < 6; ++i)
      *reinterpret_cast<u16x8*>(&Kl[krow_[i]][SWZ(krow_[i], kofs_[i])]) = kreg[i];
#pragma unroll
    for (int i = 0; i < 4; ++i)
      *reinterpret_cast<u16x8*>(&Vl[vrow_[i]][SWZ(vrow_[i], vofs_[i])]) = vreg[i];
    if (kt + 1 < ktiles) {
      const int nb = kbase + 64;
#pragma unroll
      for (int i = 0; i < 6; ++i)
        kreg[i] = *reinterpret_cast<const u16x8*>(kfh + (size_t)(nb + krow_[i]) * QKD + kofs_[i]);
#pragma unroll
      for (int i = 0; i < 4; ++i)
        vreg[i] = *reinterpret_cast<const u16x8*>(vth + (size_t)vrow_[i] * S + nb + vofs_[i]);
    }
    asm volatile("s_waitcnt lgkmcnt(0)" ::: "memory");
    __builtin_amdgcn_s_barrier();

    f32x4 sacc[4];
#pragma unroll
    for (int nf = 0; nf < 4; ++nf) sacc[nf] = {0.f, 0.f, 0.f, 0.f};
    __builtin_amdgcn_s_setprio(1);
#pragma unroll
    for (int nf = 0; nf < 4; ++nf)
#pragma unroll
      for (int dk = 0; dk < 6; ++dk) {
        int krow = nf * 16 + lr;
        bf16x8 b = *reinterpret_cast<const bf16x8*>(&Kl[krow][SWZ(krow, dk * 32 + lk * 8)]);
        sacc[nf] = __builtin_amdgcn_mfma_f32_16x16x32_bf16(qfrag[dk], b, sacc[nf], 0, 0, 0);
      }
    __builtin_amdgcn_s_setprio(0);

    float sv[4][4];
    float rowmax[4] = {-__builtin_inff(), -__builtin_inff(), -__builtin_inff(), -__builtin_inff()};
#pragma unroll
    for (int nf = 0; nf < 4; ++nf) {
      int kcol = kbase + nf * 16 + lr;
#pragma unroll
      for (int r = 0; r < 4; ++r) {
        float v = sacc[nf][r] * SCALING;
        int qrow_g = qbase + wave * 16 + lk * 4 + r;
        if (kcol > qrow_g) v = -__builtin_inff();
        sv[nf][r] = v;
        rowmax[r] = fmaxf(rowmax[r], v);
      }
    }
#pragma unroll
    for (int r = 0; r < 4; ++r) {
#pragma unroll
      for (int off = 1; off < 16; off <<= 1)
        rowmax[r] = fmaxf(rowmax[r], __shfl_xor(rowmax[r], off));
    }
    // T13 defer-max: skip rescale while per-tile max growth <= 8
    float needm = fmaxf(fmaxf(rowmax[0] - m_[0], rowmax[1] - m_[1]),
                        fmaxf(rowmax[2] - m_[2], rowmax[3] - m_[3]));
    if (!__all(needm <= 8.0f)) {
#pragma unroll
      for (int r = 0; r < 4; ++r) {
        float mn = fmaxf(m_[r], rowmax[r]);
        float alpha = __expf(m_[r] - mn);
        m_[r] = mn;
        l_[r] *= alpha;
#pragma unroll
        for (int f = 0; f < 8; ++f) o[f][r] *= alpha;
      }
    }
    float rowsum[4] = {0.f, 0.f, 0.f, 0.f};
#pragma unroll
    for (int nf = 0; nf < 4; ++nf)
#pragma unroll
      for (int r = 0; r < 4; ++r) {
        float p = __expf(sv[nf][r] - m_[r]);
        sv[nf][r] = p;
        rowsum[r] += p;
      }
#pragma unroll
    for (int r = 0; r < 4; ++r) {
#pragma unroll
      for (int off = 1; off < 16; off <<= 1) rowsum[r] += __shfl_xor(rowsum[r], off);
      l_[r] += rowsum[r];
    }
#pragma unroll
    for (int nf = 0; nf < 4; ++nf)
#pragma unroll
      for (int r = 0; r < 4; ++r) {
        int prow = lk * 4 + r;
        Pl[wave][prow][SWZ(prow, nf * 16 + lr)] = f2b(sv[nf][r]);
      }

    __builtin_amdgcn_s_setprio(1);
#pragma unroll
    for (int kk = 0; kk < 2; ++kk) {
      bf16x8 pa = *reinterpret_cast<const bf16x8*>(&Pl[wave][lr][SWZ(lr, kk * 32 + lk * 8)]);
#pragma unroll
      for (int f = 0; f < 8; ++f) {
        int vrow = f * 16 + lr;
        bf16x8 b = *reinterpret_cast<const bf16x8*>(&Vl[vrow][SWZ(vrow, kk * 32 + lk * 8)]);
        o[f] = __builtin_amdgcn_mfma_f32_16x16x32_bf16(pa, b, o[f], 0, 0, 0);
      }
    }
    __builtin_amdgcn_s_setprio(0);
  }

#pragma unroll
  for (int f = 0; f < 8; ++f)
#pragma unroll
    for (int r = 0; r < 4; ++r) {
      int row = qbase + wave * 16 + lk * 4 + r;
      float val = o[f][r] / l_[r];
      attn[(size_t)row * (H * VD) + h * VD + f * 16 + lr] = f2b(val);
    }
}

// ---------------- host launch ----------------
extern "C" void kernel_launch(void* const* d_in, const int* in_sizes, int n_in,
                              void* d_out, int out_size, void* d_ws, size_t ws_size,
                              hipStream_t stream) {
  (void)in_sizes; (void)n_in; (void)out_size; (void)ws_size;
  const float* hidden    = (const float*)d_in[1];
  const float* w_q_a     = (const float*)d_in[2];
  const float* q_a_ln_w  = (const float*)d_in[3];
  const float* w_q_b     = (const float*)d_in[4];
  const float* w_kv_a    = (const float*)d_in[5];
  const float* kv_a_ln_w = (const float*)d_in[6];
  const float* w_kv_b    = (const float*)d_in[7];
  const float* w_o       = (const float*)d_in[8];
  float* out = (float*)d_out;

  char* ws = (char*)d_ws;
  size_t off = 0;
  auto alloc = [&](size_t bytes) {
    size_t o = off;
    off += (bytes + 255) & ~(size_t)255;
    return o;
  };
  constexpr int KVA_PAD = 640;  // 576 padded to multiple of 128 (unguarded DMA)
  size_t o_hs    = alloc((size_t)S * HIDDEN * 2);        // hs bf16; later reused as qf
  size_t o_btqa  = alloc((size_t)QLORA * HIDDEN * 2);    // later (with o_btkva) bt_o
  size_t o_btkva = alloc((size_t)KVA_PAD * HIDDEN * 2);
  size_t o_btqb  = alloc((size_t)(H * QKD) * QLORA * 2);
  size_t o_btkvb = alloc((size_t)(H * 256) * KVLORA * 2);
  size_t o_qlat0 = alloc((size_t)S * QLORA * 4);         // later reused as attn
  size_t o_qlat1 = alloc((size_t)S * QLORA * 4);
  size_t o_lat0  = alloc((size_t)S * KVA_N * 4);
  size_t o_lat1  = alloc((size_t)S * KVA_N * 4);
  size_t o_qln   = alloc((size_t)S * QLORA * 2);
  size_t o_kvln  = alloc((size_t)S * KVLORA * 2);
  size_t o_qn    = alloc((size_t)S * (H * QKD) * 2);
  size_t o_kv    = alloc((size_t)S * (H * 256) * 2);
  size_t o_kf    = alloc((size_t)H * S * QKD * 2);
  size_t o_vt    = alloc((size_t)H * VD * S * 2);
  size_t o_cs    = alloc((size_t)S * 32 * 4);
  size_t o_sn    = alloc((size_t)S * 32 * 4);

  u16* hs_bf  = (u16*)(ws + o_hs);
  u16* bt_qa  = (u16*)(ws + o_btqa);
  u16* bt_kva = (u16*)(ws + o_btkva);
  u16* bt_qb  = (u16*)(ws + o_btqb);
  u16* bt_kvb = (u16*)(ws + o_btkvb);
  float* q_lat0 = (float*)(ws + o_qlat0);
  float* q_lat1 = (float*)(ws + o_qlat1);
  float* lat0   = (float*)(ws + o_lat0);
  float* lat1   = (float*)(ws + o_lat1);
  u16* q_ln  = (u16*)(ws + o_qln);
  u16* kv_ln = (u16*)(ws + o_kvln);
  u16* qn    = (u16*)(ws + o_qn);
  u16* kvb   = (u16*)(ws + o_kv);
  u16* kf    = (u16*)(ws + o_kf);
  u16* vt    = (u16*)(ws + o_vt);
  float* cs = (float*)(ws + o_cs);
  float* sn = (float*)(ws + o_sn);
  // aliases (lifetimes verified: source buffers dead before alias written)
  u16* qf   = (u16*)(ws + o_hs);
  u16* bt_o = (u16*)(ws + o_btqa);  // spans btqa+btkva (21 MB needed, 23 avail)
  u16* attn = (u16*)(ws + o_qlat0);

  // 1. fused prep: convert + 4 weight transposes + rope tables (27712 blocks)
  k_prep<<<dim3(27712), dim3(256), 0, stream>>>(hidden, hs_bf, w_q_a, bt_qa,
                                                w_kv_a, bt_kva, w_q_b, bt_qb,
                                                w_kv_b, bt_kvb, cs, sn);

  // 2. down-projections: split-K=2, 34x16 = 544 blocks (R4-proven)
  k_gemm_dp<<<dim3(34, S / 128), dim3(256), 0, stream>>>(hs_bf, bt_qa, bt_kva,
                                                         q_lat0, q_lat1, lat0, lat1);

  // 3. fused mid: rmsnorms (split-K reduce) + w_o transpose (14336 blocks)
  k_mid<<<dim3(14336), dim3(256), 0, stream>>>(q_lat0, q_lat1, q_a_ln_w, q_ln,
                                               lat0, lat1, kv_a_ln_w, kv_ln,
                                               w_o, bt_o);

  // 4. up-projections: G3 (N=3072,K=1536) + G4 (N=4096,K=512), 896 blocks
  k_gemm2<u16><<<dim3((H * QKD) / 128 + (H * 256) / 128, S / 128), dim3(256), 0, stream>>>(
      q_ln, bt_qb, qn, H * QKD, QLORA, (H * QKD) / 128,
      kv_ln, bt_kvb, kvb, H * 256, KVLORA);

  // 5. fused build: qf/kf + RoPE + vt transpose (6144 blocks)
  k_build<<<dim3(6144), dim3(256), 0, stream>>>(qn, kvb, lat0, lat1, cs, sn, qf, kf, vt);

  // 6. attention (flat 512-block grid, work-balanced qt mapping)
  k_attn<<<dim3(512), dim3(256), 0, stream>>>(qf, kf, vt, attn);

  // 7. output projection (640 blocks)
  k_gemm<float><<<dim3(HIDDEN / 128, S / 128), dim3(256), 0, stream>>>(attn, bt_o, out, HIDDEN, H * VD);
}

// Round 8
// 331.648 us; speedup vs baseline: 1.3082x; 1.0813x over previous
//
#include <hip/hip_runtime.h>
#include <math.h>

typedef unsigned short u16;
typedef unsigned int u32;
typedef __attribute__((ext_vector_type(4))) float f32x4;
typedef __attribute__((ext_vector_type(8))) unsigned short u16x8;
typedef __attribute__((ext_vector_type(4))) unsigned short u16x4;
typedef __attribute__((ext_vector_type(8))) __bf16 bf16x8;

#define DEV __device__ __forceinline__

constexpr int S = 2048;
constexpr int HIDDEN = 5120;
constexpr int H = 16;
constexpr int NOPE = 128, ROPE_D = 64, VD = 128;
constexpr int QKD = NOPE + ROPE_D;  // 192
constexpr int QLORA = 1536, KVLORA = 512;
constexpr int KVA_N = KVLORA + ROPE_D;  // 576
constexpr float SCALING = 0.11472134f;

DEV u16 f2b(float f) {
  u32 u = __builtin_bit_cast(u32, f);
  u32 r = u + 0x7FFFu + ((u >> 16) & 1u);
  return (u16)(r >> 16);
}
DEV float b2f(u16 h) { return __builtin_bit_cast(float, (u32)h << 16); }

DEV void store_out(float* p, float v) { *p = v; }
DEV void store_out(u16* p, float v) { *p = f2b(v); }

DEV void gload_lds16(const u16* g, u16* l) {
  auto* gp = (const __attribute__((address_space(1))) u16*)g;
  auto* lp = (__attribute__((address_space(3))) u16*)l;
  __builtin_amdgcn_global_load_lds(gp, lp, 16, 0, 0);
}

#define SWZ(row, col) ((col) ^ (((row) & 7) << 3))

// ================= fused prep: convert + 4 transposes + rope tables ========
DEV void transpose_tile(const float* __restrict__ in, u16* __restrict__ out,
                        int R, int C, int c0, int r0, int tid, float (*tl)[33]) {
  int tx = tid & 31, ty = tid >> 5;
  for (int r = ty; r < 32; r += 8)
    tl[r][tx] = in[(size_t)(r0 + r) * C + c0 + tx];
  __syncthreads();
  for (int r = ty; r < 32; r += 8)
    out[(size_t)(c0 + r) * R + r0 + tx] = f2b(tl[tx][r]);
}

__global__ __launch_bounds__(256) void k_prep(const float* __restrict__ hidden, u16* __restrict__ hs_bf,
                                              const float* __restrict__ w_q_a, u16* __restrict__ bt_qa,
                                              const float* __restrict__ w_kv_a, u16* __restrict__ bt_kva,
                                              const float* __restrict__ w_q_b, u16* __restrict__ bt_qb,
                                              const float* __restrict__ w_kv_b, u16* __restrict__ bt_kvb,
                                              float* __restrict__ cs, float* __restrict__ sn) {
  __shared__ float tl[32][33];
  int b = blockIdx.x, tid = threadIdx.x;
  if (b < 10240) {  // convert
    int i = (b * 256 + tid) * 4;
    f32x4 v = *reinterpret_cast<const f32x4*>(hidden + i);
    u16x4 o;
    o[0] = f2b(v[0]); o[1] = f2b(v[1]); o[2] = f2b(v[2]); o[3] = f2b(v[3]);
    *reinterpret_cast<u16x4*>(hs_bf + i) = o;
    return;
  }
  b -= 10240;
  if (b < 7680) {
    transpose_tile(w_q_a, bt_qa, HIDDEN, QLORA, (b % 48) * 32, (b / 48) * 32, tid, tl);
    return;
  }
  b -= 7680;
  if (b < 2880) {
    transpose_tile(w_kv_a, bt_kva, HIDDEN, KVA_N, (b % 18) * 32, (b / 18) * 32, tid, tl);
    return;
  }
  b -= 2880;
  if (b < 4608) {
    transpose_tile(w_q_b, bt_qb, QLORA, H * QKD, (b % 96) * 32, (b / 96) * 32, tid, tl);
    return;
  }
  b -= 4608;
  if (b < 2048) {
    transpose_tile(w_kv_b, bt_kvb, KVLORA, H * 256, (b % 128) * 32, (b / 128) * 32, tid, tl);
    return;
  }
  b -= 2048;  // rope tables, b < 256
  int idx = b * 256 + tid;
  int s = idx >> 5, j = idx & 31;
  double pf = pow(10000.0, (double)j / 32.0);
  double inv_extra = 1.0 / pf;
  double inv_interp = 1.0 / (40.0 * pf);
  double twopi = 6.283185307179586476925286766559;
  double lnb2 = 2.0 * log(10000.0);
  double lowd = floor(64.0 * log(4096.0 / (32.0 * twopi)) / lnb2);
  if (lowd < 0.0) lowd = 0.0;
  double highd = ceil(64.0 * log(4096.0 / twopi) / lnb2);
  if (highd > 63.0) highd = 63.0;
  double denom = highd - lowd;
  if (denom < 0.001) denom = 0.001;
  double ramp = ((double)j - lowd) / denom;
  ramp = ramp < 0.0 ? 0.0 : (ramp > 1.0 ? 1.0 : ramp);
  float invf = (float)(inv_interp * ramp + inv_extra * (1.0 - ramp));
  float fr = (float)s * invf;
  cs[idx] = cosf(fr);
  sn[idx] = sinf(fr);
}

// ================= bf16 GEMM body (R4-proven): 2-deep dbuf + counted vmcnt ==
template <typename OutT>
DEV void gemm_body(u16* Al, u16* Bl, const u16* __restrict__ A,
                   const u16* __restrict__ BT, OutT* __restrict__ C,
                   int N, int Kstride, int Klen, int mbase, int nbase) {
  const int tid = threadIdx.x;
  const int lane = tid & 63, wave = tid >> 6;
  const int wr = wave >> 1, wc = wave & 1;
  const int lr = lane & 15, lk = lane >> 4;
  const int srow = wave * 32 + (lane >> 2);
  const int skoff = (((lane & 3) ^ ((lane >> 3) & 3))) * 8;  // source swizzle
  const int swlk8 = (lk ^ ((lr >> 1) & 3)) * 8;              // read swizzle
  const u16* aptr = A + (size_t)(mbase + srow) * Kstride + skoff;
  const u16* bptr = BT + (size_t)(nbase + srow) * Kstride + skoff;
  u16* alw = Al + wave * (32 * 32);
  u16* blw = Bl + wave * (32 * 32);

  auto STAGE = [&](int b, int kk) {
    gload_lds16(aptr + kk, alw + b * 4096);
    gload_lds16(aptr + (size_t)16 * Kstride + kk, alw + b * 4096 + 16 * 32);
    gload_lds16(bptr + kk, blw + b * 4096);
    gload_lds16(bptr + (size_t)16 * Kstride + kk, blw + b * 4096 + 16 * 32);
  };

  f32x4 acc[4][4];
#pragma unroll
  for (int mf = 0; mf < 4; ++mf)
#pragma unroll
    for (int nf = 0; nf < 4; ++nf) acc[mf][nf] = {0.f, 0.f, 0.f, 0.f};

  const int nt = Klen >> 5;
  STAGE(0, 0);
  STAGE(1, 32);
  for (int t = 0; t < nt; ++t) {
    const int cur = t & 1;
    if (t + 1 < nt)
      asm volatile("s_waitcnt vmcnt(4)" ::: "memory");
    else
      asm volatile("s_waitcnt vmcnt(0)" ::: "memory");
    __builtin_amdgcn_s_barrier();
    const u16* Ac = Al + cur * 4096;
    const u16* Bc = Bl + cur * 4096;
    bf16x8 af[4], bfr[4];
#pragma unroll
    for (int mf = 0; mf < 4; ++mf)
      af[mf] = *reinterpret_cast<const bf16x8*>(Ac + (wr * 64 + mf * 16 + lr) * 32 + swlk8);
#pragma unroll
    for (int nf = 0; nf < 4; ++nf)
      bfr[nf] = *reinterpret_cast<const bf16x8*>(Bc + (wc * 64 + nf * 16 + lr) * 32 + swlk8);
#pragma unroll
    for (int mf = 0; mf < 4; ++mf)
#pragma unroll
      for (int nf = 0; nf < 4; ++nf)
        acc[mf][nf] = __builtin_amdgcn_mfma_f32_16x16x32_bf16(af[mf], bfr[nf], acc[mf][nf], 0, 0, 0);
    __builtin_amdgcn_s_barrier();
    if (t + 2 < nt) STAGE(cur, (t + 2) * 32);
  }

#pragma unroll
  for (int mf = 0; mf < 4; ++mf)
#pragma unroll
    for (int nf = 0; nf < 4; ++nf) {
      int col = nbase + wc * 64 + nf * 16 + lr;
      if (col < N) {
#pragma unroll
        for (int r = 0; r < 4; ++r) {
          int row = mbase + wr * 64 + mf * 16 + lk * 4 + r;
          store_out(&C[(size_t)row * N + col], acc[mf][nf][r]);
        }
      }
    }
}

// out-proj: flat 640 = 40 cols x 16 rows, row inner (XCD keeps its A rows in L2)
__global__ __launch_bounds__(256) void k_gemm_out(const u16* __restrict__ A,
                                                  const u16* __restrict__ BT,
                                                  float* __restrict__ C) {
  __shared__ u16 Al[2 * 128 * 32];
  __shared__ u16 Bl[2 * 128 * 32];
  int id = blockIdx.x;
  int row = id & 15, col = id >> 4;
  gemm_body(Al, Bl, A, BT, C, HIDDEN, H * VD, H * VD, row * 128, col * 128);
}

// up-proj grouped: flat 896 = 56 cols x 16 rows, row inner.
__global__ __launch_bounds__(256) void k_gemm_up(const u16* __restrict__ Aq, const u16* __restrict__ Bq,
                                                 u16* __restrict__ Cq,
                                                 const u16* __restrict__ Akv, const u16* __restrict__ Bkv,
                                                 u16* __restrict__ Ckv) {
  __shared__ u16 Al[2 * 128 * 32];
  __shared__ u16 Bl[2 * 128 * 32];
  int id = blockIdx.x;
  int row = id & 15, col = id >> 4;  // col 0..55
  if (col < 24)
    gemm_body(Al, Bl, Aq, Bq, Cq, H * QKD, QLORA, QLORA, row * 128, col * 128);
  else
    gemm_body(Al, Bl, Akv, Bkv, Ckv, H * 256, KVLORA, KVLORA, row * 128, (col - 24) * 128);
}

// down-proj, split-K=2: flat 544 = 2 splits x 17 cols x 16 rows, row inner.
__global__ __launch_bounds__(256) void k_gemm_dp(const u16* __restrict__ A,
                                                 const u16* __restrict__ Bq,
                                                 const u16* __restrict__ Bkv,
                                                 float* __restrict__ q0, float* __restrict__ q1,
                                                 float* __restrict__ l0, float* __restrict__ l1) {
  __shared__ u16 Al[2 * 128 * 32];
  __shared__ u16 Bl[2 * 128 * 32];
  constexpr int KH = HIDDEN / 2;  // 2560
  int id = blockIdx.x;
  int split = id >= 272;
  int u = id - split * 272;
  int row = u & 15, colt = u >> 4;  // colt 0..16
  const u16* As = A + split * KH;
  if (colt < 12) {
    gemm_body(Al, Bl, As, Bq + split * KH, split ? q1 : q0, QLORA, HIDDEN, KH,
              row * 128, colt * 128);
  } else {
    gemm_body(Al, Bl, As, Bkv + split * KH, split ? l1 : l0, KVA_N, HIDDEN, KH,
              row * 128, (colt - 12) * 128);
  }
}

// ================= fused mid: 2x rmsnorm(split-K reduce) + w_o transpose ====
DEV void rmsnorm2_row(const float* __restrict__ x0, const float* __restrict__ x1,
                      const float* __restrict__ w, u16* __restrict__ y,
                      int ncols, int instride, int row, int tid, float* red) {
  const float* xr0 = x0 + (size_t)row * instride;
  const float* xr1 = x1 + (size_t)row * instride;
  float ss = 0.f;
  for (int i = tid * 4; i < ncols; i += 1024) {
    f32x4 a = *reinterpret_cast<const f32x4*>(xr0 + i);
    f32x4 b = *reinterpret_cast<const f32x4*>(xr1 + i);
    f32x4 v = a + b;
    ss += v[0] * v[0] + v[1] * v[1] + v[2] * v[2] + v[3] * v[3];
  }
  for (int off = 32; off > 0; off >>= 1) ss += __shfl_down(ss, off);
  if ((tid & 63) == 0) red[tid >> 6] = ss;
  __syncthreads();
  ss = red[0] + red[1] + red[2] + red[3];
  float sc = rsqrtf(ss / (float)ncols + 1e-6f);
  u16* yr = y + (size_t)row * ncols;
  for (int i = tid * 4; i < ncols; i += 1024) {
    f32x4 a = *reinterpret_cast<const f32x4*>(xr0 + i);
    f32x4 b = *reinterpret_cast<const f32x4*>(xr1 + i);
    f32x4 v = a + b;
    u16x4 o;
    o[0] = f2b(v[0] * sc * w[i]);
    o[1] = f2b(v[1] * sc * w[i + 1]);
    o[2] = f2b(v[2] * sc * w[i + 2]);
    o[3] = f2b(v[3] * sc * w[i + 3]);
    *reinterpret_cast<u16x4*>(yr + i) = o;
  }
}

__global__ __launch_bounds__(256) void k_mid(const float* __restrict__ q0, const float* __restrict__ q1,
                                             const float* __restrict__ qw, u16* __restrict__ q_ln,
                                             const float* __restrict__ l0, const float* __restrict__ l1,
                                             const float* __restrict__ kw, u16* __restrict__ kv_ln,
                                             const float* __restrict__ w_o, u16* __restrict__ bt_o) {
  __shared__ float red[4];
  __shared__ float tl[32][33];
  int b = blockIdx.x, tid = threadIdx.x;
  if (b < 2048) {
    rmsnorm2_row(q0, q1, qw, q_ln, QLORA, QLORA, b, tid, red);
    return;
  }
  if (b < 4096) {
    rmsnorm2_row(l0, l1, kw, kv_ln, KVLORA, KVA_N, b - 2048, tid, red);
    return;
  }
  int u = b - 4096;  // w_o transpose: R=2048, C=5120, 160x64 tiles
  transpose_tile(w_o, bt_o, H * VD, HIDDEN, (u % 160) * 32, (u / 160) * 32, tid, tl);
}

// ================= fused build: qf/kf (+RoPE) + vt transpose ================
__global__ __launch_bounds__(256) void k_build(const u16* __restrict__ qn,
                                               const u16* __restrict__ kv,
                                               const float* __restrict__ lat0,
                                               const float* __restrict__ lat1,
                                               const float* __restrict__ cs,
                                               const float* __restrict__ sn,
                                               u16* __restrict__ qf, u16* __restrict__ kf,
                                               u16* __restrict__ vt) {
  __shared__ u16 tv[32][33];
  int b = blockIdx.x, tid = threadIdx.x;
  if (b < 2048) {
    int s = b;
    for (int idx = tid; idx < H * NOPE; idx += 256) {
      int h = idx >> 7, dd = idx & 127;
      qf[((size_t)h * S + s) * QKD + dd] = qn[(size_t)s * (H * QKD) + h * QKD + dd];
      kf[((size_t)h * S + s) * QKD + dd] = kv[(size_t)s * (H * 256) + h * 256 + dd];
    }
    for (int idx = tid; idx < H * 32; idx += 256) {
      int h = idx >> 5, j = idx & 31;
      float c = cs[s * 32 + j], si = sn[s * 32 + j];
      float x1 = b2f(qn[(size_t)s * (H * QKD) + h * QKD + NOPE + 2 * j]);
      float x2 = b2f(qn[(size_t)s * (H * QKD) + h * QKD + NOPE + 2 * j + 1]);
      qf[((size_t)h * S + s) * QKD + NOPE + 2 * j] = f2b(x1 * c - x2 * si);
      qf[((size_t)h * S + s) * QKD + NOPE + 2 * j + 1] = f2b(x2 * c + x1 * si);
      float k1 = lat0[(size_t)s * KVA_N + KVLORA + 2 * j] + lat1[(size_t)s * KVA_N + KVLORA + 2 * j];
      float k2 = lat0[(size_t)s * KVA_N + KVLORA + 2 * j + 1] + lat1[(size_t)s * KVA_N + KVLORA + 2 * j + 1];
      kf[((size_t)h * S + s) * QKD + NOPE + 2 * j] = f2b(k1 * c - k2 * si);
      kf[((size_t)h * S + s) * QKD + NOPE + 2 * j + 1] = f2b(k2 * c + k1 * si);
    }
    return;
  }
  int bb = b - 2048;  // vt: [64 s-tiles][4 d-tiles][16 heads]
  int s0 = (bb & 63) * 32, d0 = ((bb >> 6) & 3) * 32, h = bb >> 8;
  int tx = tid & 31, ty = tid >> 5;
  for (int r = ty; r < 32; r += 8)
    tv[r][tx] = kv[(size_t)(s0 + r) * (H * 256) + h * 256 + NOPE + d0 + tx];
  __syncthreads();
  for (int r = ty; r < 32; r += 8)
    vt[((size_t)h * VD + d0 + r) * S + s0 + tx] = tv[tx][r];
}

// ================= flash attention (causal), per head =======================
__global__ __launch_bounds__(256) void k_attn(const u16* __restrict__ qf,
                                              const u16* __restrict__ kf,
                                              const u16* __restrict__ vt,
                                              u16* __restrict__ attn) {
  const int bidx = blockIdx.x;
  const int j = bidx & 31;
  const int h = bidx >> 5;
  const int qt = (h < 8) ? j : 31 - j;
  const int qbase = qt * 64;
  const int tid = threadIdx.x, wave = tid >> 6, lane = tid & 63;
  const int lr = lane & 15, lk = lane >> 4;
  __shared__ u16 Kl[64][192];
  __shared__ u16 Vl[128][64];
  __shared__ u16 Pl[4][16][64];

  int krow_[6], kofs_[6], vrow_[4], vofs_[4];
#pragma unroll
  for (int i = 0; i < 6; ++i) { int c = tid + i * 256; krow_[i] = c / 24; kofs_[i] = (c % 24) * 8; }
#pragma unroll
  for (int i = 0; i < 4; ++i) { int c = tid + i * 256; vrow_[i] = c >> 3; vofs_[i] = (c & 7) * 8; }
  const u16* kfh = kf + (size_t)h * S * QKD;
  const u16* vth = vt + (size_t)h * VD * S;

  bf16x8 qfrag[6];
  const u16* qrow = qf + ((size_t)h * S + qbase + wave * 16 + lr) * QKD;
#pragma unroll
  for (int d = 0; d < 6; ++d)
    qfrag[d] = *reinterpret_cast<const bf16x8*>(qrow + d * 32 + lk * 8);

  u16x8 kreg[6], vreg[4];
#pragma unroll
  for (int i = 0; i < 6; ++i)
    kreg[i] = *reinterpret_cast<const u16x8*>(kfh + (size_t)krow_[i] * QKD + kofs_[i]);
#pragma unroll
  for (int i = 0; i < 4; ++i)
    vreg[i] = *reinterpret_cast<const u16x8*>(vth + (size_t)vrow_[i] * S + vofs_[i]);

  f32x4 o[8];
#pragma unroll
  for (int f = 0; f < 8; ++f) o[f] = {0.f, 0.f, 0.f, 0.f};
  float m_[4] = {-__builtin_inff(), -__builtin_inff(), -__builtin_inff(), -__builtin_inff()};
  float l_[4] = {0.f, 0.f, 0.f, 0.f};

  const int ktiles = qt + 1;
  for (int kt = 0; kt < ktiles; ++kt) {
    const int kbase = kt * 64;
    __builtin_amdgcn_s_barrier();
#pragma unroll
    for (int i = 0; i < 6; ++i)
      *reinterpret_cast<u16x8*>(&Kl[krow_[i]][SWZ(krow_[i], kofs_[i])]) = kreg[i];
#pragma unroll
    for (int i = 0; i < 4; ++i)
      *reinterpret_cast<u16x8*>(&Vl[vrow_[i]][SWZ(vrow_[i], vofs_[i])]) = vreg[i];
    if (kt + 1 < ktiles) {
      const int nb = kbase + 64;
#pragma unroll
      for (int i = 0; i < 6; ++i)
        kreg[i] = *reinterpret_cast<const u16x8*>(kfh + (size_t)(nb + krow_[i]) * QKD + kofs_[i]);
#pragma unroll
      for (int i = 0; i < 4; ++i)
        vreg[i] = *reinterpret_cast<const u16x8*>(vth + (size_t)vrow_[i] * S + nb + vofs_[i]);
    }
    asm volatile("s_waitcnt lgkmcnt(0)" ::: "memory");
    __builtin_amdgcn_s_barrier();

    f32x4 sacc[4];
#pragma unroll
    for (int nf = 0; nf < 4; ++nf) sacc[nf] = {0.f, 0.f, 0.f, 0.f};
    __builtin_amdgcn_s_setprio(1);
#pragma unroll
    for (int nf = 0; nf < 4; ++nf)
#pragma unroll
      for (int dk = 0; dk < 6; ++dk) {
        int krow = nf * 16 + lr;
        bf16x8 b = *reinterpret_cast<const bf16x8*>(&Kl[krow][SWZ(krow, dk * 32 + lk * 8)]);
        sacc[nf] = __builtin_amdgcn_mfma_f32_16x16x32_bf16(qfrag[dk], b, sacc[nf], 0, 0, 0);
      }
    __builtin_amdgcn_s_setprio(0);

    float sv[4][4];
    float rowmax[4] = {-__builtin_inff(), -__builtin_inff(), -__builtin_inff(), -__builtin_inff()};
#pragma unroll
    for (int nf = 0; nf < 4; ++nf) {
      int kcol = kbase + nf * 16 + lr;
#pragma unroll
      for (int r = 0; r < 4; ++r) {
        float v = sacc[nf][r] * SCALING;
        int qrow_g = qbase + wave * 16 + lk * 4 + r;
        if (kcol > qrow_g) v = -__builtin_inff();
        sv[nf][r] = v;
        rowmax[r] = fmaxf(rowmax[r], v);
      }
    }
#pragma unroll
    for (int r = 0; r < 4; ++r) {
#pragma unroll
      for (int off = 1; off < 16; off <<= 1)
        rowmax[r] = fmaxf(rowmax[r], __shfl_xor(rowmax[r], off));
    }
    // T13 defer-max: skip rescale while per-tile max growth <= 8
    float needm = fmaxf(fmaxf(rowmax[0] - m_[0], rowmax[1] - m_[1]),
                        fmaxf(rowmax[2] - m_[2], rowmax[3] - m_[3]));
    if (!__all(needm <= 8.0f)) {
#pragma unroll
      for (int r = 0; r < 4; ++r) {
        float mn = fmaxf(m_[r], rowmax[r]);
        float alpha = __expf(m_[r] - mn);
        m_[r] = mn;
        l_[r] *= alpha;
#pragma unroll
        for (int f = 0; f < 8; ++f) o[f][r] *= alpha;
      }
    }
    float rowsum[4] = {0.f, 0.f, 0.f, 0.f};
#pragma unroll
    for (int nf = 0; nf < 4; ++nf)
#pragma unroll
      for (int r = 0; r < 4; ++r) {
        float p = __expf(sv[nf][r] - m_[r]);
        sv[nf][r] = p;
        rowsum[r] += p;
      }
#pragma unroll
    for (int r = 0; r < 4; ++r) {
#pragma unroll
      for (int off = 1; off < 16; off <<= 1) rowsum[r] += __shfl_xor(rowsum[r], off);
      l_[r] += rowsum[r];
    }
#pragma unroll
    for (int nf = 0; nf < 4; ++nf)
#pragma unroll
      for (int r = 0; r < 4; ++r) {
        int prow = lk * 4 + r;
        Pl[wave][prow][SWZ(prow, nf * 16 + lr)] = f2b(sv[nf][r]);
      }

    __builtin_amdgcn_s_setprio(1);
#pragma unroll
    for (int kk = 0; kk < 2; ++kk) {
      bf16x8 pa = *reinterpret_cast<const bf16x8*>(&Pl[wave][lr][SWZ(lr, kk * 32 + lk * 8)]);
#pragma unroll
      for (int f = 0; f < 8; ++f) {
        int vrow = f * 16 + lr;
        bf16x8 b = *reinterpret_cast<const bf16x8*>(&Vl[vrow][SWZ(vrow, kk * 32 + lk * 8)]);
        o[f] = __builtin_amdgcn_mfma_f32_16x16x32_bf16(pa, b, o[f], 0, 0, 0);
      }
    }
    __builtin_amdgcn_s_setprio(0);
  }

#pragma unroll
  for (int f = 0; f < 8; ++f)
#pragma unroll
    for (int r = 0; r < 4; ++r) {
      int row = qbase + wave * 16 + lk * 4 + r;
      float val = o[f][r] / l_[r];
      attn[(size_t)row * (H * VD) + h * VD + f * 16 + lr] = f2b(val);
    }
}

// ---------------- host launch ----------------
extern "C" void kernel_launch(void* const* d_in, const int* in_sizes, int n_in,
                              void* d_out, int out_size, void* d_ws, size_t ws_size,
                              hipStream_t stream) {
  (void)in_sizes; (void)n_in; (void)out_size; (void)ws_size;
  const float* hidden    = (const float*)d_in[1];
  const float* w_q_a     = (const float*)d_in[2];
  const float* q_a_ln_w  = (const float*)d_in[3];
  const float* w_q_b     = (const float*)d_in[4];
  const float* w_kv_a    = (const float*)d_in[5];
  const float* kv_a_ln_w = (const float*)d_in[6];
  const float* w_kv_b    = (const float*)d_in[7];
  const float* w_o       = (const float*)d_in[8];
  float* out = (float*)d_out;

  char* ws = (char*)d_ws;
  size_t off = 0;
  auto alloc = [&](size_t bytes) {
    size_t o = off;
    off += (bytes + 255) & ~(size_t)255;
    return o;
  };
  constexpr int KVA_PAD = 640;  // 576 padded to multiple of 128 (unguarded DMA)
  size_t o_hs    = alloc((size_t)S * HIDDEN * 2);        // hs bf16; later reused as qf
  size_t o_btqa  = alloc((size_t)QLORA * HIDDEN * 2);    // later (with o_btkva) bt_o
  size_t o_btkva = alloc((size_t)KVA_PAD * HIDDEN * 2);
  size_t o_btqb  = alloc((size_t)(H * QKD) * QLORA * 2);
  size_t o_btkvb = alloc((size_t)(H * 256) * KVLORA * 2);
  size_t o_qlat0 = alloc((size_t)S * QLORA * 4);         // later reused as attn
  size_t o_qlat1 = alloc((size_t)S * QLORA * 4);
  size_t o_lat0  = alloc((size_t)S * KVA_N * 4);
  size_t o_lat1  = alloc((size_t)S * KVA_N * 4);
  size_t o_qln   = alloc((size_t)S * QLORA * 2);
  size_t o_kvln  = alloc((size_t)S * KVLORA * 2);
  size_t o_qn    = alloc((size_t)S * (H * QKD) * 2);
  size_t o_kv    = alloc((size_t)S * (H * 256) * 2);
  size_t o_kf    = alloc((size_t)H * S * QKD * 2);
  size_t o_vt    = alloc((size_t)H * VD * S * 2);
  size_t o_cs    = alloc((size_t)S * 32 * 4);
  size_t o_sn    = alloc((size_t)S * 32 * 4);

  u16* hs_bf  = (u16*)(ws + o_hs);
  u16* bt_qa  = (u16*)(ws + o_btqa);
  u16* bt_kva = (u16*)(ws + o_btkva);
  u16* bt_qb  = (u16*)(ws + o_btqb);
  u16* bt_kvb = (u16*)(ws + o_btkvb);
  float* q_lat0 = (float*)(ws + o_qlat0);
  float* q_lat1 = (float*)(ws + o_qlat1);
  float* lat0   = (float*)(ws + o_lat0);
  float* lat1   = (float*)(ws + o_lat1);
  u16* q_ln  = (u16*)(ws + o_qln);
  u16* kv_ln = (u16*)(ws + o_kvln);
  u16* qn    = (u16*)(ws + o_qn);
  u16* kvb   = (u16*)(ws + o_kv);
  u16* kf    = (u16*)(ws + o_kf);
  u16* vt    = (u16*)(ws + o_vt);
  float* cs = (float*)(ws + o_cs);
  float* sn = (float*)(ws + o_sn);
  // aliases (lifetimes verified: source buffers dead before alias written)
  u16* qf   = (u16*)(ws + o_hs);
  u16* bt_o = (u16*)(ws + o_btqa);  // spans btqa+btkva
  u16* attn = (u16*)(ws + o_qlat0);

  // 1. fused prep: convert + 4 weight transposes + rope tables (27712 blocks)
  k_prep<<<dim3(27712), dim3(256), 0, stream>>>(hidden, hs_bf, w_q_a, bt_qa,
                                                w_kv_a, bt_kva, w_q_b, bt_qb,
                                                w_kv_b, bt_kvb, cs, sn);

  // 2. down-projections: split-K=2, flat 544, row-inner mapping (L2 pinning)
  k_gemm_dp<<<dim3(544), dim3(256), 0, stream>>>(hs_bf, bt_qa, bt_kva,
                                                 q_lat0, q_lat1, lat0, lat1);

  // 3. fused mid: rmsnorms (split-K reduce) + w_o transpose (14336 blocks)
  k_mid<<<dim3(14336), dim3(256), 0, stream>>>(q_lat0, q_lat1, q_a_ln_w, q_ln,
                                               lat0, lat1, kv_a_ln_w, kv_ln,
                                               w_o, bt_o);

  // 4. up-projections: flat 896, row-inner mapping
  k_gemm_up<<<dim3(896), dim3(256), 0, stream>>>(q_ln, bt_qb, qn, kv_ln, bt_kvb, kvb);

  // 5. fused build: qf/kf + RoPE + vt transpose (6144 blocks)
  k_build<<<dim3(6144), dim3(256), 0, stream>>>(qn, kvb, lat0, lat1, cs, sn, qf, kf, vt);

  // 6. attention (flat 512-block grid, work-balanced qt mapping)
  k_attn<<<dim3(512), dim3(256), 0, stream>>>(qf, kf, vt, attn);

  // 7. output projection: flat 640, row-inner mapping
  k_gemm_out<<<dim3(640), dim3(256), 0, stream>>>(attn, bt_o, out);
}